// Round 4
// baseline (399.346 us; speedup 1.0000x reference)
//
#include <hip/hip_runtime.h>
#include <hip/hip_fp16.h>

#define HID 64
#define BKT_SHIFT 10
#define BKT_NODES 1024
#define PCHUNKS 512

typedef _Float16 half8 __attribute__((ext_vector_type(8)));
typedef _Float16 half4 __attribute__((ext_vector_type(4)));
typedef float f32x4 __attribute__((ext_vector_type(4)));
typedef float f32x2 __attribute__((ext_vector_type(2)));

// ---------------- pass A: per-(bucket, block) histogram ----------------
__global__ __launch_bounds__(256) void k_bkt_count(const int* __restrict__ dst,
                                                   int* __restrict__ G, int E,
                                                   int nbkt, int chunk) {
  __shared__ int hist[128];
  int p = blockIdx.x, tid = threadIdx.x;
  for (int i = tid; i < nbkt; i += 256) hist[i] = 0;
  __syncthreads();
  int s = p * chunk, e = min(s + chunk, E);
  for (int i = s + tid; i < e; i += 256) atomicAdd(&hist[dst[i] >> BKT_SHIFT], 1);
  __syncthreads();
  for (int b = tid; b < nbkt; b += 256) G[b * PCHUNKS + p] = hist[b];
}

// ---------------- generic exclusive scan (3-kernel), 1024 elems/block ---------
__global__ void k_scan1(const int* __restrict__ in, int* __restrict__ scanout,
                        int* __restrict__ blocksums, int n) {
  __shared__ int sdata[256];
  int tid = threadIdx.x;
  int base = blockIdx.x * 1024 + tid * 4;
  int v0 = 0, v1 = 0, v2 = 0, v3 = 0;
  if (base + 0 < n) v0 = in[base + 0];
  if (base + 1 < n) v1 = in[base + 1];
  if (base + 2 < n) v2 = in[base + 2];
  if (base + 3 < n) v3 = in[base + 3];
  int tsum = v0 + v1 + v2 + v3;
  sdata[tid] = tsum;
  __syncthreads();
  for (int off = 1; off < 256; off <<= 1) {
    int t = (tid >= off) ? sdata[tid - off] : 0;
    __syncthreads();
    sdata[tid] += t;
    __syncthreads();
  }
  int excl = sdata[tid] - tsum;
  if (base + 0 < n) scanout[base + 0] = excl;
  if (base + 1 < n) scanout[base + 1] = excl + v0;
  if (base + 2 < n) scanout[base + 2] = excl + v0 + v1;
  if (base + 3 < n) scanout[base + 3] = excl + v0 + v1 + v2;
  if (tid == 255) blocksums[blockIdx.x] = sdata[255];
}

__global__ void k_scan2(int* blocksums, int nb) {
  __shared__ int s[128];
  int tid = threadIdx.x;
  int v = (tid < nb) ? blocksums[tid] : 0;
  s[tid] = v;
  __syncthreads();
  for (int off = 1; off < 128; off <<= 1) {
    int t = (tid >= off) ? s[tid - off] : 0;
    __syncthreads();
    s[tid] += t;
    __syncthreads();
  }
  if (tid < nb) blocksums[tid] = s[tid] - v;
}

__global__ void k_scan3(const int* __restrict__ scanout,
                        const int* __restrict__ blocksums, int* __restrict__ outp,
                        int n) {
  int i = blockIdx.x * blockDim.x + threadIdx.x;
  if (i < n) outp[i] = scanout[i] + blocksums[i >> 10];
}

// ---------------- pass C: partition edges into bucket-ordered arrays ----------
// Also records the original edge id so the CSR-ordered edge MLP can scatter
// its output back to original edge order.
__global__ __launch_bounds__(256) void k_bkt_scatter(
    const int* __restrict__ src, const int* __restrict__ dst,
    const int* __restrict__ Gscan, int* __restrict__ psrc,
    unsigned short* __restrict__ pdst, int* __restrict__ peid, int E, int nbkt,
    int chunk) {
  __shared__ int gbase[128];
  __shared__ int rcnt[128];
  int p = blockIdx.x, tid = threadIdx.x;
  for (int b = tid; b < nbkt; b += 256) {
    gbase[b] = Gscan[b * PCHUNKS + p];
    rcnt[b] = 0;
  }
  __syncthreads();
  int s = p * chunk, e = min(s + chunk, E);
  for (int i = s + tid; i < e; i += 256) {
    int d = dst[i];
    int b = d >> BKT_SHIFT;
    int r = atomicAdd(&rcnt[b], 1);
    int pos = gbase[b] + r;
    psrc[pos] = src[i];
    pdst[pos] = (unsigned short)(d & (BKT_NODES - 1));
    peid[pos] = i;
  }
}

// ---------------- pass D: per-bucket CSR finalize (rowoff, dis, csr_src, eid) -
__global__ __launch_bounds__(1024) void k_bkt_final(
    const int* __restrict__ Gscan, const int* __restrict__ psrc,
    const unsigned short* __restrict__ pdst, const int* __restrict__ peid,
    int* __restrict__ rowoff, float* __restrict__ dis, int* __restrict__ csr_src,
    int* __restrict__ csr_eid, int E, int nbkt, int N) {
  __shared__ int cnt[BKT_NODES];
  __shared__ int lo[BKT_NODES];
  int b = blockIdx.x, tid = threadIdx.x;
  int s = Gscan[b * PCHUNKS];
  int eend = (b + 1 < nbkt) ? Gscan[(b + 1) * PCHUNKS] : E;
  cnt[tid] = 0;
  __syncthreads();
  for (int i = s + tid; i < eend; i += 1024) atomicAdd(&cnt[pdst[i]], 1);
  __syncthreads();
  int v = cnt[tid];
  lo[tid] = v;
  __syncthreads();
  for (int off = 1; off < 1024; off <<= 1) {
    int t = (tid >= off) ? lo[tid - off] : 0;
    __syncthreads();
    lo[tid] += t;
    __syncthreads();
  }
  int excl = lo[tid] - v;
  int node = b * BKT_NODES + tid;
  if (node < N) {
    rowoff[node] = s + excl;
    dis[node] = rsqrtf((float)v + 1.0f);
  }
  __syncthreads();
  lo[tid] = excl;
  cnt[tid] = 0;
  __syncthreads();
  for (int i = s + tid; i < eend; i += 1024) {
    int ln = pdst[i];
    int r = atomicAdd(&cnt[ln], 1);
    int pos = s + lo[ln] + r;
    csr_src[pos] = psrc[i];
    csr_eid[pos] = peid[i];
  }
}

// ---------------- fused packing: W1, W2, UV(Wc1) frags + biasUV + y sentinel ---
__global__ void k_pack_all(const float* __restrict__ W1, const float* __restrict__ W2,
                           const float* __restrict__ Wc1, const float* __restrict__ bc1,
                           __half* __restrict__ packW1, __half* __restrict__ packW2,
                           __half* __restrict__ packUV, float* __restrict__ biasUV,
                           __half* __restrict__ ysent) {
  int b = blockIdx.x, tid = threadIdx.x;
  if (b < 4) {
    int t = b * 256 + tid;
    int f = t >> 6, L = t & 63;
    int kc = f >> 2, nb = f & 3;
    int k = 32 * kc + ((L >> 4) << 3);
    int n = (L & 15) + 16 * nb;
    for (int j = 0; j < 8; ++j)
      packW1[(t << 3) + j] = __float2half(W1[(k + j) * 64 + n]);
  } else if (b < 6) {
    int t = (b - 4) * 256 + tid;
    int f = t >> 6, L = t & 63;
    int kc = f >> 2, nb = f & 3;
    int k = 32 * kc + ((L >> 4) << 3);
    int n = (L & 15) + 16 * nb;
    for (int j = 0; j < 8; ++j)
      packW2[(t << 3) + j] = __float2half(W2[(k + j) * 64 + n]);
  } else if (b < 10) {
    int t = (b - 6) * 256 + tid;
    int f = t >> 6, L = t & 63;
    int kc = f >> 3, nb = f & 7;
    int k = 32 * kc + ((L >> 4) << 3);
    int n = (L & 15) + 16 * nb;
    for (int j = 0; j < 8; ++j) {
      float w = (n < 64) ? Wc1[(k + j) * 64 + n] : Wc1[(64 + k + j) * 64 + (n - 64)];
      packUV[(t << 3) + j] = __float2half(w);
    }
  } else {
    if (tid < 128) biasUV[tid] = (tid < 64) ? bc1[tid] : 0.f;
    else if (tid < 192) ysent[tid - 128] = __float2half(0.f);
  }
}

// ---------------- MFMA node linear ----------------
template <int K, int NOUT, bool F32IN>
__global__ __launch_bounds__(256) void k_lin_mfma(
    const void* __restrict__ Xv, const __half* __restrict__ packB,
    const float* __restrict__ bias, const float* __restrict__ dis,
    __half* __restrict__ Y, int n) {
  int wid = blockIdx.x * 4 + (threadIdx.x >> 6);
  int rowbase = wid * 16;
  if (rowbase >= n) return;
  int L = threadIdx.x & 63;
  int m16 = L & 15, quad = L >> 4;
  constexpr int KC = K / 32;
  constexpr int NB = NOUT / 16;

  half8 Bf[KC * NB];
  const half8* packv = (const half8*)packB;
#pragma unroll
  for (int f = 0; f < KC * NB; ++f) Bf[f] = packv[f * 64 + L];

  int r = min(rowbase + m16, n - 1);
  half8 Af[KC];
  if (F32IN) {
    const float* xr = (const float*)Xv + (long)r * K;
#pragma unroll
    for (int kc = 0; kc < KC; ++kc) {
      const float4* xp = (const float4*)(xr + kc * 32 + quad * 8);
      float4 a = xp[0], b = xp[1];
      half8 v = {(_Float16)a.x, (_Float16)a.y, (_Float16)a.z, (_Float16)a.w,
                 (_Float16)b.x, (_Float16)b.y, (_Float16)b.z, (_Float16)b.w};
      Af[kc] = v;
    }
  } else {
    const half8* xr = (const half8*)((const __half*)Xv + (long)r * K);
#pragma unroll
    for (int kc = 0; kc < KC; ++kc) Af[kc] = xr[kc * 4 + quad];
  }

  f32x4 acc[NB];
#pragma unroll
  for (int nb = 0; nb < NB; ++nb) acc[nb] = {0.f, 0.f, 0.f, 0.f};
#pragma unroll
  for (int kc = 0; kc < KC; ++kc)
#pragma unroll
    for (int nb = 0; nb < NB; ++nb)
      acc[nb] = __builtin_amdgcn_mfma_f32_16x16x32_f16(Af[kc], Bf[kc * NB + nb],
                                                       acc[nb], 0, 0, 0);

  float dv[4];
#pragma unroll
  for (int j = 0; j < 4; ++j) {
    int ro = rowbase + quad * 4 + j;
    dv[j] = (dis && ro < n) ? dis[ro] : 1.f;
  }
#pragma unroll
  for (int nb = 0; nb < NB; ++nb) {
    int col = m16 + 16 * nb;
    float bv = bias ? bias[col] : 0.f;
#pragma unroll
    for (int j = 0; j < 4; ++j) {
      int ro = rowbase + quad * 4 + j;
      if (ro < n) {
        float v = (acc[nb][j] + bv) * dv[j];
        Y[(long)ro * NOUT + col] = __float2half(v);
      }
    }
  }
}

// ---------------- CSR aggregation: A = dd * (Yh[node] + sum Yh[s]) + b --------
__global__ __launch_bounds__(256) void k_agg_csr(
    const __half* __restrict__ Yh, const float* __restrict__ dis,
    const int* __restrict__ rowoff, const int* __restrict__ csr_src,
    const float* __restrict__ b, __half* __restrict__ A, int n, int E, int relu) {
  int node = blockIdx.x * 4 + (threadIdx.x >> 6);
  if (node >= n) return;
  int L = threadIdx.x & 63;
  int sub = L >> 4;
  int cq = L & 15;
  const half4* Y4 = (const half4*)Yh;
  float dd = dis[node];
  int i0 = rowoff[node];
  int end = (node == n - 1) ? E : rowoff[node + 1];

  float z[4][4] = {{0.f}};
  if (sub == 0) {
    half4 hv = Y4[(long)node * 16 + cq];
#pragma unroll
    for (int j = 0; j < 4; ++j) z[0][j] = (float)hv[j];
  }

  int last = end - 1;
  for (int base = i0; base < end; base += 16) {
    int sidx[4];
#pragma unroll
    for (int slot = 0; slot < 4; ++slot) {
      int idx = base + slot * 4 + sub;
      int sl = csr_src[min(idx, last)];
      sidx[slot] = (idx < end) ? sl : n;
    }
#pragma unroll
    for (int slot = 0; slot < 4; ++slot) {
      half4 hv = Y4[(long)sidx[slot] * 16 + cq];
#pragma unroll
      for (int j = 0; j < 4; ++j) z[slot][j] += (float)hv[j];
    }
  }

  float a[4];
#pragma unroll
  for (int j = 0; j < 4; ++j) {
    a[j] = (z[0][j] + z[1][j]) + (z[2][j] + z[3][j]);
    a[j] += __shfl_xor(a[j], 16, 64);
    a[j] += __shfl_xor(a[j], 32, 64);
  }
  if (sub == 0) {
    float4 bb = ((const float4*)b)[cq];
    float v0 = fmaf(a[0], dd, bb.x), v1 = fmaf(a[1], dd, bb.y);
    float v2 = fmaf(a[2], dd, bb.z), v3 = fmaf(a[3], dd, bb.w);
    if (relu) {
      v0 = fmaxf(v0, 0.f); v1 = fmaxf(v1, 0.f);
      v2 = fmaxf(v2, 0.f); v3 = fmaxf(v3, 0.f);
    }
    half4 o = {(_Float16)v0, (_Float16)v1, (_Float16)v2, (_Float16)v3};
    ((half4*)A)[(long)node * 16 + cq] = o;
  }
}

// ---------------- edge MLP in CSR (dst-major) order ---------------------------
// One wave per dst node: V[dst] loaded ONCE into registers (coalesced 12.8 MB
// total instead of ~88 MB of random V gathers). Only U[src] stays random.
// Output scatters to original edge order via csr_eid.
__global__ __launch_bounds__(256) void k_edge_mlp_csr(
    const __half* __restrict__ UV, const int* __restrict__ rowoff,
    const int* __restrict__ csr_src, const int* __restrict__ csr_eid,
    const float* __restrict__ Wc2, const float* __restrict__ bc2,
    float* __restrict__ out, int n, int E) {
  int node = blockIdx.x * 4 + (threadIdx.x >> 6);
  if (node >= n) return;
  int L = threadIdx.x & 63;
  int g = L >> 3;   // edge slot within group of 8
  int cg = L & 7;   // channel group: channels cg*8 .. cg*8+7

  float w0[8], w1[8];
#pragma unroll
  for (int j = 0; j < 8; ++j) {
    int c = cg * 8 + j;
    w0[j] = Wc2[2 * c];
    w1[j] = Wc2[2 * c + 1];
  }
  float ob0 = bc2[0], ob1 = bc2[1];

  const half8* UV8 = (const half8*)UV;  // row = 16 half8: U in [0,8), V in [8,16)
  half8 vv = UV8[(long)node * 16 + 8 + cg];  // this node's V chunk, in regs
  const half8 hzero = {(_Float16)0, (_Float16)0, (_Float16)0, (_Float16)0,
                       (_Float16)0, (_Float16)0, (_Float16)0, (_Float16)0};

  int i0 = rowoff[node];
  int end = (node == n - 1) ? E : rowoff[node + 1];
  int last = end - 1;

  for (int base = i0; base < end; base += 8) {
    int idx = base + g;
    int ec = min(idx, last);
    int s = __builtin_nontemporal_load(&csr_src[ec]);
    int eid = __builtin_nontemporal_load(&csr_eid[ec]);
    half8 uu = UV8[(long)s * 16 + cg];
    half8 t = uu + vv;                          // v_pk_add_f16 x4
    t = __builtin_elementwise_max(t, hzero);    // v_pk_max_f16 x4
    float o0 = 0.f, o1 = 0.f;
#pragma unroll
    for (int j = 0; j < 8; ++j) {
      float tv = (float)t[j];
      o0 = fmaf(tv, w0[j], o0);
      o1 = fmaf(tv, w1[j], o1);
    }
    // reduce across the 8 channel-group lanes of this edge
    o0 += __shfl_xor(o0, 1, 64);
    o1 += __shfl_xor(o1, 1, 64);
    o0 += __shfl_xor(o0, 2, 64);
    o1 += __shfl_xor(o1, 2, 64);
    o0 += __shfl_xor(o0, 4, 64);
    o1 += __shfl_xor(o1, 4, 64);
    if (cg == 0 && idx < end) {
      f32x2 o = {o0 + ob0, o1 + ob1};
      __builtin_nontemporal_store(o, (f32x2*)(out + 2 * (long)eid));
    }
  }
}

// ---------------- launch ----------------
extern "C" void kernel_launch(void* const* d_in, const int* in_sizes, int n_in,
                              void* d_out, int out_size, void* d_ws, size_t ws_size,
                              hipStream_t stream) {
  const float* x   = (const float*)d_in[0];
  const int*   ei  = (const int*)d_in[1];
  const float* W1  = (const float*)d_in[2];
  const float* b1  = (const float*)d_in[3];
  const float* W2  = (const float*)d_in[4];
  const float* b2  = (const float*)d_in[5];
  const float* Wc1 = (const float*)d_in[6];
  const float* bc1 = (const float*)d_in[7];
  const float* Wc2 = (const float*)d_in[8];
  const float* bc2 = (const float*)d_in[9];

  const int N = in_sizes[0] / 128;
  const int E = in_sizes[1] / 2;
  const int* src = ei;
  const int* dst = ei + E;

  const int nbkt = (N + BKT_NODES - 1) >> BKT_SHIFT;   // 98
  const int gsz = nbkt * PCHUNKS;                       // 50176
  const int chunk = (E + PCHUNKS - 1) / PCHUNKS;        // 3125

  // workspace layout
  float* dis     = (float*)d_ws;                   // N f32
  __half* y      = (__half*)(dis + N);             // (N+1)*64 f16 (sentinel row N)
  __half* h      = y + (long)(N + 1) * HID;        // N*64 f16
  __half* UV     = h + (long)N * HID;              // N*128 f16
  __half* packW1 = UV + (long)N * 128;             // 8192 f16
  __half* packW2 = packW1 + 8192;                  // 4096 f16
  __half* packUV = packW2 + 4096;                  // 8192 f16
  float* biasUV  = (float*)(packUV + 8192);        // 128 f32
  int* rowoff    = (int*)(biasUV + 128);           // N
  int* csr_src   = rowoff + N;                     // E
  int* G         = csr_src + E;                    // gsz
  int* Gs1       = G + gsz;                        // gsz
  int* Gbs       = Gs1 + gsz;                      // 128
  int* Gscan     = Gbs + 128;                      // gsz
  int* csr_eid   = Gscan + gsz;                    // E (lives until edge MLP)
  // partitioned edge arrays alias UV (dead until after k_bkt_final)
  int* psrc            = (int*)UV;                 // E ints (6.4MB)
  unsigned short* pdst = (unsigned short*)(psrc + E);  // E u16 (3.2MB)
  int* peid            = (int*)(pdst + E);         // E ints (6.4MB; 16MB < 25.6MB)

  const int B = 256;
  int nbScan = (gsz + 1023) / 1024;   // 49

  // ---- packing + bucketed CSR build (no global atomics) ----
  k_pack_all<<<11, B, 0, stream>>>(W1, W2, Wc1, bc1, packW1, packW2, packUV,
                                   biasUV, y + (long)N * HID);
  k_bkt_count<<<PCHUNKS, B, 0, stream>>>(dst, G, E, nbkt, chunk);
  k_scan1<<<nbScan, B, 0, stream>>>(G, Gs1, Gbs, gsz);
  k_scan2<<<1, 128, 0, stream>>>(Gbs, nbScan);
  k_scan3<<<(gsz + B - 1) / B, B, 0, stream>>>(Gs1, Gbs, Gscan, gsz);
  k_bkt_scatter<<<PCHUNKS, B, 0, stream>>>(src, dst, Gscan, psrc, pdst, peid, E,
                                           nbkt, chunk);
  k_bkt_final<<<nbkt, 1024, 0, stream>>>(Gscan, psrc, pdst, peid, rowoff, dis,
                                         csr_src, csr_eid, E, nbkt, N);

  int gAgg = (N + 3) / 4;
  int gLin = (N + 63) / 64;

  // ---- layer 1: y = (x@W1)*dis ; h = relu(dd*(y_self+sum y) + b1) ----
  k_lin_mfma<128, 64, true><<<gLin, B, 0, stream>>>(x, packW1, nullptr, dis, y, N);
  k_agg_csr<<<gAgg, B, 0, stream>>>(y, dis, rowoff, csr_src, b1, h, N, E, 1);

  // ---- layer 2 ----
  k_lin_mfma<64, 64, false><<<gLin, B, 0, stream>>>(h, packW2, nullptr, dis, y, N);
  k_agg_csr<<<gAgg, B, 0, stream>>>(y, dis, rowoff, csr_src, b2, h, N, E, 0);

  // ---- classifier: UV = [h@Wc1a + bc1 | h@Wc1b] ; CSR-ordered edge MLP ----
  k_lin_mfma<64, 128, false><<<gLin, B, 0, stream>>>(h, packUV, biasUV, nullptr, UV, N);
  k_edge_mlp_csr<<<gAgg, B, 0, stream>>>(UV, rowoff, csr_src, csr_eid, Wc2, bc2,
                                         (float*)d_out, N, E);
}

// Round 5
// 374.096 us; speedup vs baseline: 1.0675x; 1.0675x over previous
//
#include <hip/hip_runtime.h>
#include <hip/hip_fp16.h>

#define HID 64
#define BKT_SHIFT 10
#define BKT_NODES 1024
#define PCHUNKS 512

typedef _Float16 half8 __attribute__((ext_vector_type(8)));
typedef _Float16 half4 __attribute__((ext_vector_type(4)));
typedef float f32x4 __attribute__((ext_vector_type(4)));
typedef float f32x2 __attribute__((ext_vector_type(2)));

// ---------------- pass A: per-(bucket, block) histogram ----------------
__global__ __launch_bounds__(256) void k_bkt_count(const int* __restrict__ dst,
                                                   int* __restrict__ G, int E,
                                                   int nbkt, int chunk) {
  __shared__ int hist[128];
  int p = blockIdx.x, tid = threadIdx.x;
  for (int i = tid; i < nbkt; i += 256) hist[i] = 0;
  __syncthreads();
  int s = p * chunk, e = min(s + chunk, E);
  for (int i = s + tid; i < e; i += 256) atomicAdd(&hist[dst[i] >> BKT_SHIFT], 1);
  __syncthreads();
  for (int b = tid; b < nbkt; b += 256) G[b * PCHUNKS + p] = hist[b];
}

// ---------------- generic exclusive scan (3-kernel), 1024 elems/block ---------
__global__ void k_scan1(const int* __restrict__ in, int* __restrict__ scanout,
                        int* __restrict__ blocksums, int n) {
  __shared__ int sdata[256];
  int tid = threadIdx.x;
  int base = blockIdx.x * 1024 + tid * 4;
  int v0 = 0, v1 = 0, v2 = 0, v3 = 0;
  if (base + 0 < n) v0 = in[base + 0];
  if (base + 1 < n) v1 = in[base + 1];
  if (base + 2 < n) v2 = in[base + 2];
  if (base + 3 < n) v3 = in[base + 3];
  int tsum = v0 + v1 + v2 + v3;
  sdata[tid] = tsum;
  __syncthreads();
  for (int off = 1; off < 256; off <<= 1) {
    int t = (tid >= off) ? sdata[tid - off] : 0;
    __syncthreads();
    sdata[tid] += t;
    __syncthreads();
  }
  int excl = sdata[tid] - tsum;
  if (base + 0 < n) scanout[base + 0] = excl;
  if (base + 1 < n) scanout[base + 1] = excl + v0;
  if (base + 2 < n) scanout[base + 2] = excl + v0 + v1;
  if (base + 3 < n) scanout[base + 3] = excl + v0 + v1 + v2;
  if (tid == 255) blocksums[blockIdx.x] = sdata[255];
}

__global__ void k_scan2(int* blocksums, int nb) {
  __shared__ int s[128];
  int tid = threadIdx.x;
  int v = (tid < nb) ? blocksums[tid] : 0;
  s[tid] = v;
  __syncthreads();
  for (int off = 1; off < 128; off <<= 1) {
    int t = (tid >= off) ? s[tid - off] : 0;
    __syncthreads();
    s[tid] += t;
    __syncthreads();
  }
  if (tid < nb) blocksums[tid] = s[tid] - v;
}

__global__ void k_scan3(const int* __restrict__ scanout,
                        const int* __restrict__ blocksums, int* __restrict__ outp,
                        int n) {
  int i = blockIdx.x * blockDim.x + threadIdx.x;
  if (i < n) outp[i] = scanout[i] + blocksums[i >> 10];
}

// ---------------- pass C: partition edges into bucket-ordered arrays ----------
__global__ __launch_bounds__(256) void k_bkt_scatter(
    const int* __restrict__ src, const int* __restrict__ dst,
    const int* __restrict__ Gscan, int* __restrict__ psrc,
    unsigned short* __restrict__ pdst, int E, int nbkt, int chunk) {
  __shared__ int gbase[128];
  __shared__ int rcnt[128];
  int p = blockIdx.x, tid = threadIdx.x;
  for (int b = tid; b < nbkt; b += 256) {
    gbase[b] = Gscan[b * PCHUNKS + p];
    rcnt[b] = 0;
  }
  __syncthreads();
  int s = p * chunk, e = min(s + chunk, E);
  for (int i = s + tid; i < e; i += 256) {
    int d = dst[i];
    int b = d >> BKT_SHIFT;
    int r = atomicAdd(&rcnt[b], 1);
    int pos = gbase[b] + r;
    psrc[pos] = src[i];
    pdst[pos] = (unsigned short)(d & (BKT_NODES - 1));
  }
}

// ---------------- pass D: per-bucket CSR finalize (rowoff, dis, csr_src) ------
__global__ __launch_bounds__(1024) void k_bkt_final(
    const int* __restrict__ Gscan, const int* __restrict__ psrc,
    const unsigned short* __restrict__ pdst, int* __restrict__ rowoff,
    float* __restrict__ dis, int* __restrict__ csr_src, int E, int nbkt, int N) {
  __shared__ int cnt[BKT_NODES];
  __shared__ int lo[BKT_NODES];
  int b = blockIdx.x, tid = threadIdx.x;
  int s = Gscan[b * PCHUNKS];
  int eend = (b + 1 < nbkt) ? Gscan[(b + 1) * PCHUNKS] : E;
  cnt[tid] = 0;
  __syncthreads();
  for (int i = s + tid; i < eend; i += 1024) atomicAdd(&cnt[pdst[i]], 1);
  __syncthreads();
  int v = cnt[tid];
  lo[tid] = v;
  __syncthreads();
  for (int off = 1; off < 1024; off <<= 1) {
    int t = (tid >= off) ? lo[tid - off] : 0;
    __syncthreads();
    lo[tid] += t;
    __syncthreads();
  }
  int excl = lo[tid] - v;
  int node = b * BKT_NODES + tid;
  if (node < N) {
    rowoff[node] = s + excl;
    dis[node] = rsqrtf((float)v + 1.0f);
  }
  __syncthreads();
  lo[tid] = excl;
  cnt[tid] = 0;
  __syncthreads();
  for (int i = s + tid; i < eend; i += 1024) {
    int ln = pdst[i];
    int r = atomicAdd(&cnt[ln], 1);
    csr_src[s + lo[ln] + r] = psrc[i];
  }
}

// ---------------- fused packing: W1, W2, UV(Wc1) frags + biasUV + y sentinel ---
__global__ void k_pack_all(const float* __restrict__ W1, const float* __restrict__ W2,
                           const float* __restrict__ Wc1, const float* __restrict__ bc1,
                           __half* __restrict__ packW1, __half* __restrict__ packW2,
                           __half* __restrict__ packUV, float* __restrict__ biasUV,
                           __half* __restrict__ ysent) {
  int b = blockIdx.x, tid = threadIdx.x;
  if (b < 4) {
    int t = b * 256 + tid;
    int f = t >> 6, L = t & 63;
    int kc = f >> 2, nb = f & 3;
    int k = 32 * kc + ((L >> 4) << 3);
    int n = (L & 15) + 16 * nb;
    for (int j = 0; j < 8; ++j)
      packW1[(t << 3) + j] = __float2half(W1[(k + j) * 64 + n]);
  } else if (b < 6) {
    int t = (b - 4) * 256 + tid;
    int f = t >> 6, L = t & 63;
    int kc = f >> 2, nb = f & 3;
    int k = 32 * kc + ((L >> 4) << 3);
    int n = (L & 15) + 16 * nb;
    for (int j = 0; j < 8; ++j)
      packW2[(t << 3) + j] = __float2half(W2[(k + j) * 64 + n]);
  } else if (b < 10) {
    int t = (b - 6) * 256 + tid;
    int f = t >> 6, L = t & 63;
    int kc = f >> 3, nb = f & 7;
    int k = 32 * kc + ((L >> 4) << 3);
    int n = (L & 15) + 16 * nb;
    for (int j = 0; j < 8; ++j) {
      float w = (n < 64) ? Wc1[(k + j) * 64 + n] : Wc1[(64 + k + j) * 64 + (n - 64)];
      packUV[(t << 3) + j] = __float2half(w);
    }
  } else {
    if (tid < 128) biasUV[tid] = (tid < 64) ? bc1[tid] : 0.f;
    else if (tid < 192) ysent[tid - 128] = __float2half(0.f);
  }
}

// ---------------- MFMA node linear ----------------
template <int K, int NOUT, bool F32IN>
__global__ __launch_bounds__(256) void k_lin_mfma(
    const void* __restrict__ Xv, const __half* __restrict__ packB,
    const float* __restrict__ bias, const float* __restrict__ dis,
    __half* __restrict__ Y, int n) {
  int wid = blockIdx.x * 4 + (threadIdx.x >> 6);
  int rowbase = wid * 16;
  if (rowbase >= n) return;
  int L = threadIdx.x & 63;
  int m16 = L & 15, quad = L >> 4;
  constexpr int KC = K / 32;
  constexpr int NB = NOUT / 16;

  half8 Bf[KC * NB];
  const half8* packv = (const half8*)packB;
#pragma unroll
  for (int f = 0; f < KC * NB; ++f) Bf[f] = packv[f * 64 + L];

  int r = min(rowbase + m16, n - 1);
  half8 Af[KC];
  if (F32IN) {
    const float* xr = (const float*)Xv + (long)r * K;
#pragma unroll
    for (int kc = 0; kc < KC; ++kc) {
      const float4* xp = (const float4*)(xr + kc * 32 + quad * 8);
      float4 a = xp[0], b = xp[1];
      half8 v = {(_Float16)a.x, (_Float16)a.y, (_Float16)a.z, (_Float16)a.w,
                 (_Float16)b.x, (_Float16)b.y, (_Float16)b.z, (_Float16)b.w};
      Af[kc] = v;
    }
  } else {
    const half8* xr = (const half8*)((const __half*)Xv + (long)r * K);
#pragma unroll
    for (int kc = 0; kc < KC; ++kc) Af[kc] = xr[kc * 4 + quad];
  }

  f32x4 acc[NB];
#pragma unroll
  for (int nb = 0; nb < NB; ++nb) acc[nb] = {0.f, 0.f, 0.f, 0.f};
#pragma unroll
  for (int kc = 0; kc < KC; ++kc)
#pragma unroll
    for (int nb = 0; nb < NB; ++nb)
      acc[nb] = __builtin_amdgcn_mfma_f32_16x16x32_f16(Af[kc], Bf[kc * NB + nb],
                                                       acc[nb], 0, 0, 0);

  float dv[4];
#pragma unroll
  for (int j = 0; j < 4; ++j) {
    int ro = rowbase + quad * 4 + j;
    dv[j] = (dis && ro < n) ? dis[ro] : 1.f;
  }
#pragma unroll
  for (int nb = 0; nb < NB; ++nb) {
    int col = m16 + 16 * nb;
    float bv = bias ? bias[col] : 0.f;
#pragma unroll
    for (int j = 0; j < 4; ++j) {
      int ro = rowbase + quad * 4 + j;
      if (ro < n) {
        float v = (acc[nb][j] + bv) * dv[j];
        Y[(long)ro * NOUT + col] = __float2half(v);
      }
    }
  }
}

// ---------------- CSR aggregation: A = dd * (Yh[node] + sum Yh[s]) + b --------
// Widened to 32 edges / 8 gathers-per-lane in flight per iteration: random
// gather kernels on this fabric are MLP-limited (round-4 lesson), and at
// mean degree 16 most nodes now complete in a single gather round-trip.
__global__ __launch_bounds__(256) void k_agg_csr(
    const __half* __restrict__ Yh, const float* __restrict__ dis,
    const int* __restrict__ rowoff, const int* __restrict__ csr_src,
    const float* __restrict__ b, __half* __restrict__ A, int n, int E, int relu) {
  int node = blockIdx.x * 4 + (threadIdx.x >> 6);
  if (node >= n) return;
  int L = threadIdx.x & 63;
  int sub = L >> 4;
  int cq = L & 15;
  const half4* Y4 = (const half4*)Yh;
  float dd = dis[node];
  int i0 = rowoff[node];
  int end = (node == n - 1) ? E : rowoff[node + 1];

  float z[8][4] = {{0.f}};
  if (sub == 0) {
    half4 hv = Y4[(long)node * 16 + cq];
#pragma unroll
    for (int j = 0; j < 4; ++j) z[0][j] = (float)hv[j];
  }

  int last = end - 1;
  for (int base = i0; base < end; base += 32) {
    int sidx[8];
#pragma unroll
    for (int slot = 0; slot < 8; ++slot) {
      int idx = base + slot * 4 + sub;
      int sl = csr_src[min(idx, last)];
      sidx[slot] = (idx < end) ? sl : n;
    }
#pragma unroll
    for (int slot = 0; slot < 8; ++slot) {
      half4 hv = Y4[(long)sidx[slot] * 16 + cq];
#pragma unroll
      for (int j = 0; j < 4; ++j) z[slot][j] += (float)hv[j];
    }
  }

  float a[4];
#pragma unroll
  for (int j = 0; j < 4; ++j) {
    a[j] = ((z[0][j] + z[1][j]) + (z[2][j] + z[3][j])) +
           ((z[4][j] + z[5][j]) + (z[6][j] + z[7][j]));
    a[j] += __shfl_xor(a[j], 16, 64);
    a[j] += __shfl_xor(a[j], 32, 64);
  }
  if (sub == 0) {
    float4 bb = ((const float4*)b)[cq];
    float v0 = fmaf(a[0], dd, bb.x), v1 = fmaf(a[1], dd, bb.y);
    float v2 = fmaf(a[2], dd, bb.z), v3 = fmaf(a[3], dd, bb.w);
    if (relu) {
      v0 = fmaxf(v0, 0.f); v1 = fmaxf(v1, 0.f);
      v2 = fmaxf(v2, 0.f); v3 = fmaxf(v3, 0.f);
    }
    half4 o = {(_Float16)v0, (_Float16)v1, (_Float16)v2, (_Float16)v3};
    ((half4*)A)[(long)node * 16 + cq] = o;
  }
}

// ---------------- edge MLP: out_e = relu(U[src]+V[dst]) @ Wc2 + bc2 ----------
// 8 lanes per edge, half8 (16B) gathers, packed fp16 add+relu, fp32 dot.
// Original edge order: coalesced index reads and output writes.
__global__ __launch_bounds__(256) void k_edge_mlp(
    const __half* __restrict__ UV, const int* __restrict__ src,
    const int* __restrict__ dst, const float* __restrict__ Wc2,
    const float* __restrict__ bc2, float* __restrict__ out, int E, int nwaves) {
  int wid = blockIdx.x * 4 + (threadIdx.x >> 6);
  int L = threadIdx.x & 63;
  int g = L >> 3;   // edge slot within group of 8
  int cg = L & 7;   // channel group: channels cg*8 .. cg*8+7

  // per-lane fp32 weights for this lane's 8 channels
  float w0[8], w1[8];
#pragma unroll
  for (int j = 0; j < 8; ++j) {
    int c = cg * 8 + j;
    w0[j] = Wc2[2 * c];
    w1[j] = Wc2[2 * c + 1];
  }
  float ob0 = bc2[0], ob1 = bc2[1];

  const half8* UV8 = (const half8*)UV;  // row = 16 half8: U in [0,8), V in [8,16)
  int last = E - 1;
  const half8 hzero = {(_Float16)0, (_Float16)0, (_Float16)0, (_Float16)0,
                       (_Float16)0, (_Float16)0, (_Float16)0, (_Float16)0};

  for (long base = (long)wid * 32; base < E; base += (long)nwaves * 32) {
    int se[4], de[4];
#pragma unroll
    for (int s = 0; s < 4; ++s) {
      int e = (int)base + s * 8 + g;
      int ec = min(e, last);
      se[s] = __builtin_nontemporal_load(&src[ec]);
      de[s] = __builtin_nontemporal_load(&dst[ec]);
    }
    half8 uu[4], vv[4];
#pragma unroll
    for (int s = 0; s < 4; ++s) {
      uu[s] = UV8[(long)se[s] * 16 + cg];
      vv[s] = UV8[(long)de[s] * 16 + 8 + cg];
    }
#pragma unroll
    for (int s = 0; s < 4; ++s) {
      half8 t = uu[s] + vv[s];                       // v_pk_add_f16 x4
      t = __builtin_elementwise_max(t, hzero);       // v_pk_max_f16 x4
      float o0 = 0.f, o1 = 0.f;
#pragma unroll
      for (int j = 0; j < 8; ++j) {
        float tv = (float)t[j];
        o0 = fmaf(tv, w0[j], o0);
        o1 = fmaf(tv, w1[j], o1);
      }
      // reduce across the 8 lanes of this edge
      o0 += __shfl_xor(o0, 1, 64);
      o1 += __shfl_xor(o1, 1, 64);
      o0 += __shfl_xor(o0, 2, 64);
      o1 += __shfl_xor(o1, 2, 64);
      o0 += __shfl_xor(o0, 4, 64);
      o1 += __shfl_xor(o1, 4, 64);
      int e = (int)base + s * 8 + g;
      if (cg == 0 && e < E) {
        f32x2 o = {o0 + ob0, o1 + ob1};
        __builtin_nontemporal_store(o, (f32x2*)(out + 2 * (long)e));
      }
    }
  }
}

// ---------------- launch ----------------
extern "C" void kernel_launch(void* const* d_in, const int* in_sizes, int n_in,
                              void* d_out, int out_size, void* d_ws, size_t ws_size,
                              hipStream_t stream) {
  const float* x   = (const float*)d_in[0];
  const int*   ei  = (const int*)d_in[1];
  const float* W1  = (const float*)d_in[2];
  const float* b1  = (const float*)d_in[3];
  const float* W2  = (const float*)d_in[4];
  const float* b2  = (const float*)d_in[5];
  const float* Wc1 = (const float*)d_in[6];
  const float* bc1 = (const float*)d_in[7];
  const float* Wc2 = (const float*)d_in[8];
  const float* bc2 = (const float*)d_in[9];

  const int N = in_sizes[0] / 128;
  const int E = in_sizes[1] / 2;
  const int* src = ei;
  const int* dst = ei + E;

  const int nbkt = (N + BKT_NODES - 1) >> BKT_SHIFT;   // 98
  const int gsz = nbkt * PCHUNKS;                       // 50176
  const int chunk = (E + PCHUNKS - 1) / PCHUNKS;        // 3125

  // workspace layout
  float* dis     = (float*)d_ws;                   // N f32
  __half* y      = (__half*)(dis + N);             // (N+1)*64 f16 (sentinel row N)
  __half* h      = y + (long)(N + 1) * HID;        // N*64 f16
  __half* UV     = h + (long)N * HID;              // N*128 f16
  __half* packW1 = UV + (long)N * 128;             // 8192 f16
  __half* packW2 = packW1 + 8192;                  // 4096 f16
  __half* packUV = packW2 + 4096;                  // 8192 f16
  float* biasUV  = (float*)(packUV + 8192);        // 128 f32
  int* rowoff    = (int*)(biasUV + 128);           // N
  int* csr_src   = rowoff + N;                     // E
  int* G         = csr_src + E;                    // gsz
  int* Gs1       = G + gsz;                        // gsz
  int* Gbs       = Gs1 + gsz;                      // 128
  int* Gscan     = Gbs + 128;                      // gsz
  // partitioned edge arrays alias UV (dead until after k_bkt_final)
  int* psrc            = (int*)UV;                 // E ints (6.4MB < 25.6MB)
  unsigned short* pdst = (unsigned short*)(psrc + E);  // E u16

  const int B = 256;
  int nbScan = (gsz + 1023) / 1024;   // 49

  // ---- packing + bucketed CSR build (no global atomics) ----
  k_pack_all<<<11, B, 0, stream>>>(W1, W2, Wc1, bc1, packW1, packW2, packUV,
                                   biasUV, y + (long)N * HID);
  k_bkt_count<<<PCHUNKS, B, 0, stream>>>(dst, G, E, nbkt, chunk);
  k_scan1<<<nbScan, B, 0, stream>>>(G, Gs1, Gbs, gsz);
  k_scan2<<<1, 128, 0, stream>>>(Gbs, nbScan);
  k_scan3<<<(gsz + B - 1) / B, B, 0, stream>>>(Gs1, Gbs, Gscan, gsz);
  k_bkt_scatter<<<PCHUNKS, B, 0, stream>>>(src, dst, Gscan, psrc, pdst, E, nbkt,
                                           chunk);
  k_bkt_final<<<nbkt, 1024, 0, stream>>>(Gscan, psrc, pdst, rowoff, dis, csr_src,
                                         E, nbkt, N);

  int gAgg = (N + 3) / 4;
  int gLin = (N + 63) / 64;

  // ---- layer 1: y = (x@W1)*dis ; h = relu(dd*(y_self+sum y) + b1) ----
  k_lin_mfma<128, 64, true><<<gLin, B, 0, stream>>>(x, packW1, nullptr, dis, y, N);
  k_agg_csr<<<gAgg, B, 0, stream>>>(y, dis, rowoff, csr_src, b1, h, N, E, 1);

  // ---- layer 2 ----
  k_lin_mfma<64, 64, false><<<gLin, B, 0, stream>>>(h, packW2, nullptr, dis, y, N);
  k_agg_csr<<<gAgg, B, 0, stream>>>(y, dis, rowoff, csr_src, b2, h, N, E, 0);

  // ---- classifier: UV = [h@Wc1a + bc1 | h@Wc1b] ; edge MLP ----
  k_lin_mfma<64, 128, false><<<gLin, B, 0, stream>>>(h, packUV, biasUV, nullptr, UV, N);
  int cblocks = 2048;
  int nwaves = cblocks * 4;
  k_edge_mlp<<<cblocks, B, 0, stream>>>(UV, src, dst, Wc2, bc2,
                                        (float*)d_out, E, nwaves);
}

// Round 6
// 360.477 us; speedup vs baseline: 1.1078x; 1.0378x over previous
//
#include <hip/hip_runtime.h>
#include <hip/hip_fp16.h>

#define HID 64
#define BKT_SHIFT 10
#define BKT_NODES 1024
#define PCHUNKS 512

typedef _Float16 half8 __attribute__((ext_vector_type(8)));
typedef _Float16 half4 __attribute__((ext_vector_type(4)));
typedef float f32x4 __attribute__((ext_vector_type(4)));
typedef float f32x2 __attribute__((ext_vector_type(2)));

// ---------------- pass A: per-(bucket, block) histogram ----------------
__global__ __launch_bounds__(256) void k_bkt_count(const int* __restrict__ dst,
                                                   int* __restrict__ G, int E,
                                                   int nbkt, int chunk) {
  __shared__ int hist[128];
  int p = blockIdx.x, tid = threadIdx.x;
  for (int i = tid; i < nbkt; i += 256) hist[i] = 0;
  __syncthreads();
  int s = p * chunk, e = min(s + chunk, E);
  for (int i = s + tid; i < e; i += 256) atomicAdd(&hist[dst[i] >> BKT_SHIFT], 1);
  __syncthreads();
  for (int b = tid; b < nbkt; b += 256) G[b * PCHUNKS + p] = hist[b];
}

// ---------------- generic exclusive scan (3-kernel), 1024 elems/block ---------
__global__ void k_scan1(const int* __restrict__ in, int* __restrict__ scanout,
                        int* __restrict__ blocksums, int n) {
  __shared__ int sdata[256];
  int tid = threadIdx.x;
  int base = blockIdx.x * 1024 + tid * 4;
  int v0 = 0, v1 = 0, v2 = 0, v3 = 0;
  if (base + 0 < n) v0 = in[base + 0];
  if (base + 1 < n) v1 = in[base + 1];
  if (base + 2 < n) v2 = in[base + 2];
  if (base + 3 < n) v3 = in[base + 3];
  int tsum = v0 + v1 + v2 + v3;
  sdata[tid] = tsum;
  __syncthreads();
  for (int off = 1; off < 256; off <<= 1) {
    int t = (tid >= off) ? sdata[tid - off] : 0;
    __syncthreads();
    sdata[tid] += t;
    __syncthreads();
  }
  int excl = sdata[tid] - tsum;
  if (base + 0 < n) scanout[base + 0] = excl;
  if (base + 1 < n) scanout[base + 1] = excl + v0;
  if (base + 2 < n) scanout[base + 2] = excl + v0 + v1;
  if (base + 3 < n) scanout[base + 3] = excl + v0 + v1 + v2;
  if (tid == 255) blocksums[blockIdx.x] = sdata[255];
}

__global__ void k_scan2(int* blocksums, int nb) {
  __shared__ int s[128];
  int tid = threadIdx.x;
  int v = (tid < nb) ? blocksums[tid] : 0;
  s[tid] = v;
  __syncthreads();
  for (int off = 1; off < 128; off <<= 1) {
    int t = (tid >= off) ? s[tid - off] : 0;
    __syncthreads();
    s[tid] += t;
    __syncthreads();
  }
  if (tid < nb) blocksums[tid] = s[tid] - v;
}

__global__ void k_scan3(const int* __restrict__ scanout,
                        const int* __restrict__ blocksums, int* __restrict__ outp,
                        int n) {
  int i = blockIdx.x * blockDim.x + threadIdx.x;
  if (i < n) outp[i] = scanout[i] + blocksums[i >> 10];
}

// ---------------- pass C: partition edges into bucket-ordered arrays ----------
__global__ __launch_bounds__(256) void k_bkt_scatter(
    const int* __restrict__ src, const int* __restrict__ dst,
    const int* __restrict__ Gscan, int* __restrict__ psrc,
    unsigned short* __restrict__ pdst, int E, int nbkt, int chunk) {
  __shared__ int gbase[128];
  __shared__ int rcnt[128];
  int p = blockIdx.x, tid = threadIdx.x;
  for (int b = tid; b < nbkt; b += 256) {
    gbase[b] = Gscan[b * PCHUNKS + p];
    rcnt[b] = 0;
  }
  __syncthreads();
  int s = p * chunk, e = min(s + chunk, E);
  for (int i = s + tid; i < e; i += 256) {
    int d = dst[i];
    int b = d >> BKT_SHIFT;
    int r = atomicAdd(&rcnt[b], 1);
    int pos = gbase[b] + r;
    psrc[pos] = src[i];
    pdst[pos] = (unsigned short)(d & (BKT_NODES - 1));
  }
}

// ---------------- pass D: per-bucket CSR finalize (rowoff, dis, csr_src) ------
__global__ __launch_bounds__(1024) void k_bkt_final(
    const int* __restrict__ Gscan, const int* __restrict__ psrc,
    const unsigned short* __restrict__ pdst, int* __restrict__ rowoff,
    float* __restrict__ dis, int* __restrict__ csr_src, int E, int nbkt, int N) {
  __shared__ int cnt[BKT_NODES];
  __shared__ int lo[BKT_NODES];
  int b = blockIdx.x, tid = threadIdx.x;
  int s = Gscan[b * PCHUNKS];
  int eend = (b + 1 < nbkt) ? Gscan[(b + 1) * PCHUNKS] : E;
  cnt[tid] = 0;
  __syncthreads();
  for (int i = s + tid; i < eend; i += 1024) atomicAdd(&cnt[pdst[i]], 1);
  __syncthreads();
  int v = cnt[tid];
  lo[tid] = v;
  __syncthreads();
  for (int off = 1; off < 1024; off <<= 1) {
    int t = (tid >= off) ? lo[tid - off] : 0;
    __syncthreads();
    lo[tid] += t;
    __syncthreads();
  }
  int excl = lo[tid] - v;
  int node = b * BKT_NODES + tid;
  if (node < N) {
    rowoff[node] = s + excl;
    dis[node] = rsqrtf((float)v + 1.0f);
  }
  __syncthreads();
  lo[tid] = excl;
  cnt[tid] = 0;
  __syncthreads();
  for (int i = s + tid; i < eend; i += 1024) {
    int ln = pdst[i];
    int r = atomicAdd(&cnt[ln], 1);
    csr_src[s + lo[ln] + r] = psrc[i];
  }
}

// ---------------- fused packing: W1, W2, UV(Wc1) frags + biasUV + y sentinel ---
__global__ void k_pack_all(const float* __restrict__ W1, const float* __restrict__ W2,
                           const float* __restrict__ Wc1, const float* __restrict__ bc1,
                           __half* __restrict__ packW1, __half* __restrict__ packW2,
                           __half* __restrict__ packUV, float* __restrict__ biasUV,
                           __half* __restrict__ ysent) {
  int b = blockIdx.x, tid = threadIdx.x;
  if (b < 4) {
    int t = b * 256 + tid;
    int f = t >> 6, L = t & 63;
    int kc = f >> 2, nb = f & 3;
    int k = 32 * kc + ((L >> 4) << 3);
    int n = (L & 15) + 16 * nb;
    for (int j = 0; j < 8; ++j)
      packW1[(t << 3) + j] = __float2half(W1[(k + j) * 64 + n]);
  } else if (b < 6) {
    int t = (b - 4) * 256 + tid;
    int f = t >> 6, L = t & 63;
    int kc = f >> 2, nb = f & 3;
    int k = 32 * kc + ((L >> 4) << 3);
    int n = (L & 15) + 16 * nb;
    for (int j = 0; j < 8; ++j)
      packW2[(t << 3) + j] = __float2half(W2[(k + j) * 64 + n]);
  } else if (b < 10) {
    int t = (b - 6) * 256 + tid;
    int f = t >> 6, L = t & 63;
    int kc = f >> 3, nb = f & 7;
    int k = 32 * kc + ((L >> 4) << 3);
    int n = (L & 15) + 16 * nb;
    for (int j = 0; j < 8; ++j) {
      float w = (n < 64) ? Wc1[(k + j) * 64 + n] : Wc1[(64 + k + j) * 64 + (n - 64)];
      packUV[(t << 3) + j] = __float2half(w);
    }
  } else {
    if (tid < 128) biasUV[tid] = (tid < 64) ? bc1[tid] : 0.f;
    else if (tid < 192) ysent[tid - 128] = __float2half(0.f);
  }
}

// ---------------- MFMA node linear ----------------
template <int K, int NOUT, bool F32IN>
__global__ __launch_bounds__(256) void k_lin_mfma(
    const void* __restrict__ Xv, const __half* __restrict__ packB,
    const float* __restrict__ bias, const float* __restrict__ dis,
    __half* __restrict__ Y, int n) {
  int wid = blockIdx.x * 4 + (threadIdx.x >> 6);
  int rowbase = wid * 16;
  if (rowbase >= n) return;
  int L = threadIdx.x & 63;
  int m16 = L & 15, quad = L >> 4;
  constexpr int KC = K / 32;
  constexpr int NB = NOUT / 16;

  half8 Bf[KC * NB];
  const half8* packv = (const half8*)packB;
#pragma unroll
  for (int f = 0; f < KC * NB; ++f) Bf[f] = packv[f * 64 + L];

  int r = min(rowbase + m16, n - 1);
  half8 Af[KC];
  if (F32IN) {
    const float* xr = (const float*)Xv + (long)r * K;
#pragma unroll
    for (int kc = 0; kc < KC; ++kc) {
      const float4* xp = (const float4*)(xr + kc * 32 + quad * 8);
      float4 a = xp[0], b = xp[1];
      half8 v = {(_Float16)a.x, (_Float16)a.y, (_Float16)a.z, (_Float16)a.w,
                 (_Float16)b.x, (_Float16)b.y, (_Float16)b.z, (_Float16)b.w};
      Af[kc] = v;
    }
  } else {
    const half8* xr = (const half8*)((const __half*)Xv + (long)r * K);
#pragma unroll
    for (int kc = 0; kc < KC; ++kc) Af[kc] = xr[kc * 4 + quad];
  }

  f32x4 acc[NB];
#pragma unroll
  for (int nb = 0; nb < NB; ++nb) acc[nb] = {0.f, 0.f, 0.f, 0.f};
#pragma unroll
  for (int kc = 0; kc < KC; ++kc)
#pragma unroll
    for (int nb = 0; nb < NB; ++nb)
      acc[nb] = __builtin_amdgcn_mfma_f32_16x16x32_f16(Af[kc], Bf[kc * NB + nb],
                                                       acc[nb], 0, 0, 0);

  float dv[4];
#pragma unroll
  for (int j = 0; j < 4; ++j) {
    int ro = rowbase + quad * 4 + j;
    dv[j] = (dis && ro < n) ? dis[ro] : 1.f;
  }
#pragma unroll
  for (int nb = 0; nb < NB; ++nb) {
    int col = m16 + 16 * nb;
    float bv = bias ? bias[col] : 0.f;
#pragma unroll
    for (int j = 0; j < 4; ++j) {
      int ro = rowbase + quad * 4 + j;
      if (ro < n) {
        float v = (acc[nb][j] + bv) * dv[j];
        Y[(long)ro * NOUT + col] = __float2half(v);
      }
    }
  }
}

// ---------------- CSR aggregation: A = dd * (Yh[node] + sum Yh[s]) + b --------
__global__ __launch_bounds__(256) void k_agg_csr(
    const __half* __restrict__ Yh, const float* __restrict__ dis,
    const int* __restrict__ rowoff, const int* __restrict__ csr_src,
    const float* __restrict__ b, __half* __restrict__ A, int n, int E, int relu) {
  int node = blockIdx.x * 4 + (threadIdx.x >> 6);
  if (node >= n) return;
  int L = threadIdx.x & 63;
  int sub = L >> 4;
  int cq = L & 15;
  const half4* Y4 = (const half4*)Yh;
  float dd = dis[node];
  int i0 = rowoff[node];
  int end = (node == n - 1) ? E : rowoff[node + 1];

  float z[4][4] = {{0.f}};
  if (sub == 0) {
    half4 hv = Y4[(long)node * 16 + cq];
#pragma unroll
    for (int j = 0; j < 4; ++j) z[0][j] = (float)hv[j];
  }

  int last = end - 1;
  for (int base = i0; base < end; base += 16) {
    int sidx[4];
#pragma unroll
    for (int slot = 0; slot < 4; ++slot) {
      int idx = base + slot * 4 + sub;
      int sl = csr_src[min(idx, last)];
      sidx[slot] = (idx < end) ? sl : n;
    }
#pragma unroll
    for (int slot = 0; slot < 4; ++slot) {
      half4 hv = Y4[(long)sidx[slot] * 16 + cq];
#pragma unroll
      for (int j = 0; j < 4; ++j) z[slot][j] += (float)hv[j];
    }
  }

  float a[4];
#pragma unroll
  for (int j = 0; j < 4; ++j) {
    a[j] = (z[0][j] + z[1][j]) + (z[2][j] + z[3][j]);
    a[j] += __shfl_xor(a[j], 16, 64);
    a[j] += __shfl_xor(a[j], 32, 64);
  }
  if (sub == 0) {
    float4 bb = ((const float4*)b)[cq];
    float v0 = fmaf(a[0], dd, bb.x), v1 = fmaf(a[1], dd, bb.y);
    float v2 = fmaf(a[2], dd, bb.z), v3 = fmaf(a[3], dd, bb.w);
    if (relu) {
      v0 = fmaxf(v0, 0.f); v1 = fmaxf(v1, 0.f);
      v2 = fmaxf(v2, 0.f); v3 = fmaxf(v3, 0.f);
    }
    half4 o = {(_Float16)v0, (_Float16)v1, (_Float16)v2, (_Float16)v3};
    ((half4*)A)[(long)node * 16 + cq] = o;
  }
}

// ---------------- fused edge classifier via MFMA ------------------------------
// out_e = relu(h[src]@Wc1a + h[dst]@Wc1b + bc1) @ Wc2 + bc2
// One wave per 16 edges. Gathers hit the 12.8MB h table (both endpoints) =>
// coupon-collector HBM fetch halves vs the 25.6MB UV-table formulation.
// Bf layout (from k_pack_all): f = kc*8+nb; nb<4 -> Wc1a (src), nb>=4 -> Wc1b.
__global__ __launch_bounds__(256) void k_edge_mfma(
    const __half* __restrict__ H, const __half* __restrict__ packUV,
    const int* __restrict__ src, const int* __restrict__ dst,
    const float* __restrict__ bc1, const float* __restrict__ Wc2,
    const float* __restrict__ bc2, float* __restrict__ out, int E, int nwaves) {
  int wid = blockIdx.x * 4 + (threadIdx.x >> 6);
  int L = threadIdx.x & 63;
  int m16 = L & 15, quad = L >> 4;

  half8 Bf[16];
  const half8* packv = (const half8*)packUV;
#pragma unroll
  for (int f = 0; f < 16; ++f) Bf[f] = packv[f * 64 + L];

  // per-lane epilogue constants for output cols m16 + 16*nb
  float bcv[4], w0[4], w1[4];
#pragma unroll
  for (int nb = 0; nb < 4; ++nb) {
    int c = m16 + 16 * nb;
    bcv[nb] = bc1[c];
    w0[nb] = Wc2[2 * c];
    w1[nb] = Wc2[2 * c + 1];
  }
  float ob0 = bc2[0], ob1 = bc2[1];

  const half8* H8 = (const half8*)H;  // 8 half8 per 64-f16 node row

  for (long base = (long)wid * 16; base < E; base += (long)nwaves * 16) {
    int e = (int)base + m16;          // E % 16 == 0 for grid-stride chunks
    int se = __builtin_nontemporal_load(&src[e]);
    int de = __builtin_nontemporal_load(&dst[e]);
    half8 As0 = H8[(long)se * 8 + quad];
    half8 As1 = H8[(long)se * 8 + 4 + quad];
    half8 Ad0 = H8[(long)de * 8 + quad];
    half8 Ad1 = H8[(long)de * 8 + 4 + quad];

    f32x4 acc[4];
#pragma unroll
    for (int nb = 0; nb < 4; ++nb) acc[nb] = {0.f, 0.f, 0.f, 0.f};
#pragma unroll
    for (int nb = 0; nb < 4; ++nb) {
      acc[nb] = __builtin_amdgcn_mfma_f32_16x16x32_f16(As0, Bf[nb], acc[nb], 0, 0, 0);
      acc[nb] = __builtin_amdgcn_mfma_f32_16x16x32_f16(As1, Bf[8 + nb], acc[nb], 0, 0, 0);
      acc[nb] = __builtin_amdgcn_mfma_f32_16x16x32_f16(Ad0, Bf[4 + nb], acc[nb], 0, 0, 0);
      acc[nb] = __builtin_amdgcn_mfma_f32_16x16x32_f16(Ad1, Bf[12 + nb], acc[nb], 0, 0, 0);
    }

    // C layout: row(edge-in-group) = quad*4 + j, col = m16 + 16*nb
    float o0[4] = {0.f, 0.f, 0.f, 0.f}, o1[4] = {0.f, 0.f, 0.f, 0.f};
#pragma unroll
    for (int nb = 0; nb < 4; ++nb) {
#pragma unroll
      for (int j = 0; j < 4; ++j) {
        float z = fmaxf(acc[nb][j] + bcv[nb], 0.f);
        o0[j] = fmaf(z, w0[nb], o0[j]);
        o1[j] = fmaf(z, w1[nb], o1[j]);
      }
    }
#pragma unroll
    for (int j = 0; j < 4; ++j) {
      o0[j] += __shfl_xor(o0[j], 1, 64);
      o1[j] += __shfl_xor(o1[j], 1, 64);
      o0[j] += __shfl_xor(o0[j], 2, 64);
      o1[j] += __shfl_xor(o1[j], 2, 64);
      o0[j] += __shfl_xor(o0[j], 4, 64);
      o1[j] += __shfl_xor(o1[j], 4, 64);
      o0[j] += __shfl_xor(o0[j], 8, 64);
      o1[j] += __shfl_xor(o1[j], 8, 64);
    }
    if (m16 == 0) {
      long eb = base + quad * 4;
      f32x4 oa = {o0[0] + ob0, o1[0] + ob1, o0[1] + ob0, o1[1] + ob1};
      f32x4 ob_ = {o0[2] + ob0, o1[2] + ob1, o0[3] + ob0, o1[3] + ob1};
      __builtin_nontemporal_store(oa, (f32x4*)(out + 2 * eb));
      __builtin_nontemporal_store(ob_, (f32x4*)(out + 2 * eb + 4));
    }
  }
}

// ---------------- launch ----------------
extern "C" void kernel_launch(void* const* d_in, const int* in_sizes, int n_in,
                              void* d_out, int out_size, void* d_ws, size_t ws_size,
                              hipStream_t stream) {
  const float* x   = (const float*)d_in[0];
  const int*   ei  = (const int*)d_in[1];
  const float* W1  = (const float*)d_in[2];
  const float* b1  = (const float*)d_in[3];
  const float* W2  = (const float*)d_in[4];
  const float* b2  = (const float*)d_in[5];
  const float* Wc1 = (const float*)d_in[6];
  const float* bc1 = (const float*)d_in[7];
  const float* Wc2 = (const float*)d_in[8];
  const float* bc2 = (const float*)d_in[9];

  const int N = in_sizes[0] / 128;
  const int E = in_sizes[1] / 2;
  const int* src = ei;
  const int* dst = ei + E;

  const int nbkt = (N + BKT_NODES - 1) >> BKT_SHIFT;   // 98
  const int gsz = nbkt * PCHUNKS;                       // 50176
  const int chunk = (E + PCHUNKS - 1) / PCHUNKS;        // 3125

  // workspace layout
  float* dis     = (float*)d_ws;                   // N f32
  __half* y      = (__half*)(dis + N);             // (N+1)*64 f16 (sentinel row N)
  __half* h      = y + (long)(N + 1) * HID;        // N*64 f16
  __half* UV     = h + (long)N * HID;              // scratch region (aliased below)
  __half* packW1 = UV + (long)N * 128;             // 8192 f16
  __half* packW2 = packW1 + 8192;                  // 4096 f16
  __half* packUV = packW2 + 4096;                  // 8192 f16
  float* biasUV  = (float*)(packUV + 8192);        // 128 f32
  int* rowoff    = (int*)(biasUV + 128);           // N
  int* csr_src   = rowoff + N;                     // E
  int* G         = csr_src + E;                    // gsz
  int* Gs1       = G + gsz;                        // gsz
  int* Gbs       = Gs1 + gsz;                      // 128
  int* Gscan     = Gbs + 128;                      // gsz
  // partitioned edge arrays alias the (now otherwise unused) UV region
  int* psrc            = (int*)UV;                 // E ints (6.4MB < 25.6MB)
  unsigned short* pdst = (unsigned short*)(psrc + E);  // E u16

  const int B = 256;
  int nbScan = (gsz + 1023) / 1024;   // 49

  // ---- packing + bucketed CSR build (no global atomics) ----
  k_pack_all<<<11, B, 0, stream>>>(W1, W2, Wc1, bc1, packW1, packW2, packUV,
                                   biasUV, y + (long)N * HID);
  k_bkt_count<<<PCHUNKS, B, 0, stream>>>(dst, G, E, nbkt, chunk);
  k_scan1<<<nbScan, B, 0, stream>>>(G, Gs1, Gbs, gsz);
  k_scan2<<<1, 128, 0, stream>>>(Gbs, nbScan);
  k_scan3<<<(gsz + B - 1) / B, B, 0, stream>>>(Gs1, Gbs, Gscan, gsz);
  k_bkt_scatter<<<PCHUNKS, B, 0, stream>>>(src, dst, Gscan, psrc, pdst, E, nbkt,
                                           chunk);
  k_bkt_final<<<nbkt, 1024, 0, stream>>>(Gscan, psrc, pdst, rowoff, dis, csr_src,
                                         E, nbkt, N);

  int gAgg = (N + 3) / 4;
  int gLin = (N + 63) / 64;

  // ---- layer 1: y = (x@W1)*dis ; h = relu(dd*(y_self+sum y) + b1) ----
  k_lin_mfma<128, 64, true><<<gLin, B, 0, stream>>>(x, packW1, nullptr, dis, y, N);
  k_agg_csr<<<gAgg, B, 0, stream>>>(y, dis, rowoff, csr_src, b1, h, N, E, 1);

  // ---- layer 2 ----
  k_lin_mfma<64, 64, false><<<gLin, B, 0, stream>>>(h, packW2, nullptr, dis, y, N);
  k_agg_csr<<<gAgg, B, 0, stream>>>(y, dis, rowoff, csr_src, b2, h, N, E, 0);

  // ---- fused edge classifier: gathers h directly, MFMA per 16 edges ----
  int cblocks = 2048;
  int nwaves = cblocks * 4;
  k_edge_mfma<<<cblocks, B, 0, stream>>>(h, packUV, src, dst, bc1, Wc2, bc2,
                                         (float*)d_out, E, nwaves);
}

// Round 7
// 353.181 us; speedup vs baseline: 1.1307x; 1.0207x over previous
//
#include <hip/hip_runtime.h>
#include <hip/hip_fp16.h>

#define HID 64
#define BKT_SHIFT 10
#define BKT_NODES 1024
#define PCHUNKS 512

typedef _Float16 half8 __attribute__((ext_vector_type(8)));
typedef _Float16 half4 __attribute__((ext_vector_type(4)));
typedef float f32x4 __attribute__((ext_vector_type(4)));
typedef float f32x2 __attribute__((ext_vector_type(2)));

// ---------------- pass A: per-(bucket, block) histogram ----------------
__global__ __launch_bounds__(256) void k_bkt_count(const int* __restrict__ dst,
                                                   int* __restrict__ G, int E,
                                                   int nbkt, int chunk) {
  __shared__ int hist[128];
  int p = blockIdx.x, tid = threadIdx.x;
  for (int i = tid; i < nbkt; i += 256) hist[i] = 0;
  __syncthreads();
  int s = p * chunk, e = min(s + chunk, E);
  for (int i = s + tid; i < e; i += 256) atomicAdd(&hist[dst[i] >> BKT_SHIFT], 1);
  __syncthreads();
  for (int b = tid; b < nbkt; b += 256) G[b * PCHUNKS + p] = hist[b];
}

// ---------------- generic exclusive scan (3-kernel), 1024 elems/block ---------
__global__ void k_scan1(const int* __restrict__ in, int* __restrict__ scanout,
                        int* __restrict__ blocksums, int n) {
  __shared__ int sdata[256];
  int tid = threadIdx.x;
  int base = blockIdx.x * 1024 + tid * 4;
  int v0 = 0, v1 = 0, v2 = 0, v3 = 0;
  if (base + 0 < n) v0 = in[base + 0];
  if (base + 1 < n) v1 = in[base + 1];
  if (base + 2 < n) v2 = in[base + 2];
  if (base + 3 < n) v3 = in[base + 3];
  int tsum = v0 + v1 + v2 + v3;
  sdata[tid] = tsum;
  __syncthreads();
  for (int off = 1; off < 256; off <<= 1) {
    int t = (tid >= off) ? sdata[tid - off] : 0;
    __syncthreads();
    sdata[tid] += t;
    __syncthreads();
  }
  int excl = sdata[tid] - tsum;
  if (base + 0 < n) scanout[base + 0] = excl;
  if (base + 1 < n) scanout[base + 1] = excl + v0;
  if (base + 2 < n) scanout[base + 2] = excl + v0 + v1;
  if (base + 3 < n) scanout[base + 3] = excl + v0 + v1 + v2;
  if (tid == 255) blocksums[blockIdx.x] = sdata[255];
}

__global__ void k_scan2(int* blocksums, int nb) {
  __shared__ int s[128];
  int tid = threadIdx.x;
  int v = (tid < nb) ? blocksums[tid] : 0;
  s[tid] = v;
  __syncthreads();
  for (int off = 1; off < 128; off <<= 1) {
    int t = (tid >= off) ? s[tid - off] : 0;
    __syncthreads();
    s[tid] += t;
    __syncthreads();
  }
  if (tid < nb) blocksums[tid] = s[tid] - v;
}

__global__ void k_scan3(const int* __restrict__ scanout,
                        const int* __restrict__ blocksums, int* __restrict__ outp,
                        int n) {
  int i = blockIdx.x * blockDim.x + threadIdx.x;
  if (i < n) outp[i] = scanout[i] + blocksums[i >> 10];
}

// ---------------- pass C: partition edges into bucket-ordered arrays ----------
__global__ __launch_bounds__(256) void k_bkt_scatter(
    const int* __restrict__ src, const int* __restrict__ dst,
    const int* __restrict__ Gscan, int* __restrict__ psrc,
    unsigned short* __restrict__ pdst, int E, int nbkt, int chunk) {
  __shared__ int gbase[128];
  __shared__ int rcnt[128];
  int p = blockIdx.x, tid = threadIdx.x;
  for (int b = tid; b < nbkt; b += 256) {
    gbase[b] = Gscan[b * PCHUNKS + p];
    rcnt[b] = 0;
  }
  __syncthreads();
  int s = p * chunk, e = min(s + chunk, E);
  for (int i = s + tid; i < e; i += 256) {
    int d = dst[i];
    int b = d >> BKT_SHIFT;
    int r = atomicAdd(&rcnt[b], 1);
    int pos = gbase[b] + r;
    psrc[pos] = src[i];
    pdst[pos] = (unsigned short)(d & (BKT_NODES - 1));
  }
}

// ---------------- pass D: per-bucket CSR finalize (rowoff, dis, csr_src) ------
__global__ __launch_bounds__(1024) void k_bkt_final(
    const int* __restrict__ Gscan, const int* __restrict__ psrc,
    const unsigned short* __restrict__ pdst, int* __restrict__ rowoff,
    float* __restrict__ dis, int* __restrict__ csr_src, int E, int nbkt, int N) {
  __shared__ int cnt[BKT_NODES];
  __shared__ int lo[BKT_NODES];
  int b = blockIdx.x, tid = threadIdx.x;
  int s = Gscan[b * PCHUNKS];
  int eend = (b + 1 < nbkt) ? Gscan[(b + 1) * PCHUNKS] : E;
  cnt[tid] = 0;
  __syncthreads();
  for (int i = s + tid; i < eend; i += 1024) atomicAdd(&cnt[pdst[i]], 1);
  __syncthreads();
  int v = cnt[tid];
  lo[tid] = v;
  __syncthreads();
  for (int off = 1; off < 1024; off <<= 1) {
    int t = (tid >= off) ? lo[tid - off] : 0;
    __syncthreads();
    lo[tid] += t;
    __syncthreads();
  }
  int excl = lo[tid] - v;
  int node = b * BKT_NODES + tid;
  if (node < N) {
    rowoff[node] = s + excl;
    dis[node] = rsqrtf((float)v + 1.0f);
  }
  __syncthreads();
  lo[tid] = excl;
  cnt[tid] = 0;
  __syncthreads();
  for (int i = s + tid; i < eend; i += 1024) {
    int ln = pdst[i];
    int r = atomicAdd(&cnt[ln], 1);
    csr_src[s + lo[ln] + r] = psrc[i];
  }
}

// ---------------- fused packing: W1, W2, UV(Wc1) frags + biasUV + y sentinel ---
__global__ void k_pack_all(const float* __restrict__ W1, const float* __restrict__ W2,
                           const float* __restrict__ Wc1, const float* __restrict__ bc1,
                           __half* __restrict__ packW1, __half* __restrict__ packW2,
                           __half* __restrict__ packUV, float* __restrict__ biasUV,
                           __half* __restrict__ ysent) {
  int b = blockIdx.x, tid = threadIdx.x;
  if (b < 4) {
    int t = b * 256 + tid;
    int f = t >> 6, L = t & 63;
    int kc = f >> 2, nb = f & 3;
    int k = 32 * kc + ((L >> 4) << 3);
    int n = (L & 15) + 16 * nb;
    for (int j = 0; j < 8; ++j)
      packW1[(t << 3) + j] = __float2half(W1[(k + j) * 64 + n]);
  } else if (b < 6) {
    int t = (b - 4) * 256 + tid;
    int f = t >> 6, L = t & 63;
    int kc = f >> 2, nb = f & 3;
    int k = 32 * kc + ((L >> 4) << 3);
    int n = (L & 15) + 16 * nb;
    for (int j = 0; j < 8; ++j)
      packW2[(t << 3) + j] = __float2half(W2[(k + j) * 64 + n]);
  } else if (b < 10) {
    int t = (b - 6) * 256 + tid;
    int f = t >> 6, L = t & 63;
    int kc = f >> 3, nb = f & 7;
    int k = 32 * kc + ((L >> 4) << 3);
    int n = (L & 15) + 16 * nb;
    for (int j = 0; j < 8; ++j) {
      float w = (n < 64) ? Wc1[(k + j) * 64 + n] : Wc1[(64 + k + j) * 64 + (n - 64)];
      packUV[(t << 3) + j] = __float2half(w);
    }
  } else {
    if (tid < 128) biasUV[tid] = (tid < 64) ? bc1[tid] : 0.f;
    else if (tid < 192) ysent[tid - 128] = __float2half(0.f);
  }
}

// ---------------- MFMA node linear ----------------
template <int K, int NOUT, bool F32IN>
__global__ __launch_bounds__(256) void k_lin_mfma(
    const void* __restrict__ Xv, const __half* __restrict__ packB,
    const float* __restrict__ bias, const float* __restrict__ dis,
    __half* __restrict__ Y, int n) {
  int wid = blockIdx.x * 4 + (threadIdx.x >> 6);
  int rowbase = wid * 16;
  if (rowbase >= n) return;
  int L = threadIdx.x & 63;
  int m16 = L & 15, quad = L >> 4;
  constexpr int KC = K / 32;
  constexpr int NB = NOUT / 16;

  half8 Bf[KC * NB];
  const half8* packv = (const half8*)packB;
#pragma unroll
  for (int f = 0; f < KC * NB; ++f) Bf[f] = packv[f * 64 + L];

  int r = min(rowbase + m16, n - 1);
  half8 Af[KC];
  if (F32IN) {
    const float* xr = (const float*)Xv + (long)r * K;
#pragma unroll
    for (int kc = 0; kc < KC; ++kc) {
      const float4* xp = (const float4*)(xr + kc * 32 + quad * 8);
      float4 a = xp[0], b = xp[1];
      half8 v = {(_Float16)a.x, (_Float16)a.y, (_Float16)a.z, (_Float16)a.w,
                 (_Float16)b.x, (_Float16)b.y, (_Float16)b.z, (_Float16)b.w};
      Af[kc] = v;
    }
  } else {
    const half8* xr = (const half8*)((const __half*)Xv + (long)r * K);
#pragma unroll
    for (int kc = 0; kc < KC; ++kc) Af[kc] = xr[kc * 4 + quad];
  }

  f32x4 acc[NB];
#pragma unroll
  for (int nb = 0; nb < NB; ++nb) acc[nb] = {0.f, 0.f, 0.f, 0.f};
#pragma unroll
  for (int kc = 0; kc < KC; ++kc)
#pragma unroll
    for (int nb = 0; nb < NB; ++nb)
      acc[nb] = __builtin_amdgcn_mfma_f32_16x16x32_f16(Af[kc], Bf[kc * NB + nb],
                                                       acc[nb], 0, 0, 0);

  float dv[4];
#pragma unroll
  for (int j = 0; j < 4; ++j) {
    int ro = rowbase + quad * 4 + j;
    dv[j] = (dis && ro < n) ? dis[ro] : 1.f;
  }
#pragma unroll
  for (int nb = 0; nb < NB; ++nb) {
    int col = m16 + 16 * nb;
    float bv = bias ? bias[col] : 0.f;
#pragma unroll
    for (int j = 0; j < 4; ++j) {
      int ro = rowbase + quad * 4 + j;
      if (ro < n) {
        float v = (acc[nb][j] + bv) * dv[j];
        Y[(long)ro * NOUT + col] = __float2half(v);
      }
    }
  }
}

// ---------------- CSR aggregation: A = dd * (Yh[node] + sum Yh[s]) + b --------
__global__ __launch_bounds__(256) void k_agg_csr(
    const __half* __restrict__ Yh, const float* __restrict__ dis,
    const int* __restrict__ rowoff, const int* __restrict__ csr_src,
    const float* __restrict__ b, __half* __restrict__ A, int n, int E, int relu) {
  int node = blockIdx.x * 4 + (threadIdx.x >> 6);
  if (node >= n) return;
  int L = threadIdx.x & 63;
  int sub = L >> 4;
  int cq = L & 15;
  const half4* Y4 = (const half4*)Yh;
  float dd = dis[node];
  int i0 = rowoff[node];
  int end = (node == n - 1) ? E : rowoff[node + 1];

  float z[4][4] = {{0.f}};
  if (sub == 0) {
    half4 hv = Y4[(long)node * 16 + cq];
#pragma unroll
    for (int j = 0; j < 4; ++j) z[0][j] = (float)hv[j];
  }

  int last = end - 1;
  for (int base = i0; base < end; base += 16) {
    int sidx[4];
#pragma unroll
    for (int slot = 0; slot < 4; ++slot) {
      int idx = base + slot * 4 + sub;
      int sl = csr_src[min(idx, last)];
      sidx[slot] = (idx < end) ? sl : n;
    }
#pragma unroll
    for (int slot = 0; slot < 4; ++slot) {
      half4 hv = Y4[(long)sidx[slot] * 16 + cq];
#pragma unroll
      for (int j = 0; j < 4; ++j) z[slot][j] += (float)hv[j];
    }
  }

  float a[4];
#pragma unroll
  for (int j = 0; j < 4; ++j) {
    a[j] = (z[0][j] + z[1][j]) + (z[2][j] + z[3][j]);
    a[j] += __shfl_xor(a[j], 16, 64);
    a[j] += __shfl_xor(a[j], 32, 64);
  }
  if (sub == 0) {
    float4 bb = ((const float4*)b)[cq];
    float v0 = fmaf(a[0], dd, bb.x), v1 = fmaf(a[1], dd, bb.y);
    float v2 = fmaf(a[2], dd, bb.z), v3 = fmaf(a[3], dd, bb.w);
    if (relu) {
      v0 = fmaxf(v0, 0.f); v1 = fmaxf(v1, 0.f);
      v2 = fmaxf(v2, 0.f); v3 = fmaxf(v3, 0.f);
    }
    half4 o = {(_Float16)v0, (_Float16)v1, (_Float16)v2, (_Float16)v3};
    ((half4*)A)[(long)node * 16 + cq] = o;
  }
}

// ---------------- fused edge classifier via MFMA, 2-group pipelined -----------
// out_e = relu(h[src]@Wc1a + h[dst]@Wc1b + bc1) @ Wc2 + bc2
// 32 edges per grid-stride iteration: all 8 gathers (2 groups x 4) issued
// up-front so group-1 loads stay in flight during group-0 MFMAs (the compiler's
// counted vmcnt keeps them outstanding). Doubles per-wave MLP vs round 6.
// Bf layout (from k_pack_all): f = kc*8+nb; nb<4 -> Wc1a (src), nb>=4 -> Wc1b.
// Assumes E % 32 == 0 (E = 1.6M).
__global__ __launch_bounds__(256) void k_edge_mfma(
    const __half* __restrict__ H, const __half* __restrict__ packUV,
    const int* __restrict__ src, const int* __restrict__ dst,
    const float* __restrict__ bc1, const float* __restrict__ Wc2,
    const float* __restrict__ bc2, float* __restrict__ out, int E, int nwaves) {
  int wid = blockIdx.x * 4 + (threadIdx.x >> 6);
  int L = threadIdx.x & 63;
  int m16 = L & 15, quad = L >> 4;

  half8 Bf[16];
  const half8* packv = (const half8*)packUV;
#pragma unroll
  for (int f = 0; f < 16; ++f) Bf[f] = packv[f * 64 + L];

  // per-lane epilogue constants for output cols m16 + 16*nb
  float bcv[4], w0[4], w1[4];
#pragma unroll
  for (int nb = 0; nb < 4; ++nb) {
    int c = m16 + 16 * nb;
    bcv[nb] = bc1[c];
    w0[nb] = Wc2[2 * c];
    w1[nb] = Wc2[2 * c + 1];
  }
  float ob0 = bc2[0], ob1 = bc2[1];

  const half8* H8 = (const half8*)H;  // 8 half8 per 64-f16 node row

  for (long base = (long)wid * 32; base < E; base += (long)nwaves * 32) {
    int e0 = (int)base + m16;
    int e1 = (int)base + 16 + m16;
    int se0 = __builtin_nontemporal_load(&src[e0]);
    int de0 = __builtin_nontemporal_load(&dst[e0]);
    int se1 = __builtin_nontemporal_load(&src[e1]);
    int de1 = __builtin_nontemporal_load(&dst[e1]);
    // all 8 gathers issued before any MFMA
    half8 As0 = H8[(long)se0 * 8 + quad];
    half8 As1 = H8[(long)se0 * 8 + 4 + quad];
    half8 Ad0 = H8[(long)de0 * 8 + quad];
    half8 Ad1 = H8[(long)de0 * 8 + 4 + quad];
    half8 Bs0 = H8[(long)se1 * 8 + quad];
    half8 Bs1 = H8[(long)se1 * 8 + 4 + quad];
    half8 Bd0 = H8[(long)de1 * 8 + quad];
    half8 Bd1 = H8[(long)de1 * 8 + 4 + quad];

#pragma unroll
    for (int grp = 0; grp < 2; ++grp) {
      half8 s0 = grp ? Bs0 : As0, s1 = grp ? Bs1 : As1;
      half8 d0 = grp ? Bd0 : Ad0, d1 = grp ? Bd1 : Ad1;

      f32x4 acc[4];
#pragma unroll
      for (int nb = 0; nb < 4; ++nb) acc[nb] = {0.f, 0.f, 0.f, 0.f};
#pragma unroll
      for (int nb = 0; nb < 4; ++nb) {
        acc[nb] = __builtin_amdgcn_mfma_f32_16x16x32_f16(s0, Bf[nb], acc[nb], 0, 0, 0);
        acc[nb] = __builtin_amdgcn_mfma_f32_16x16x32_f16(s1, Bf[8 + nb], acc[nb], 0, 0, 0);
        acc[nb] = __builtin_amdgcn_mfma_f32_16x16x32_f16(d0, Bf[4 + nb], acc[nb], 0, 0, 0);
        acc[nb] = __builtin_amdgcn_mfma_f32_16x16x32_f16(d1, Bf[12 + nb], acc[nb], 0, 0, 0);
      }

      // C layout: row(edge-in-group) = quad*4 + j, col = m16 + 16*nb
      float o0[4] = {0.f, 0.f, 0.f, 0.f}, o1[4] = {0.f, 0.f, 0.f, 0.f};
#pragma unroll
      for (int nb = 0; nb < 4; ++nb) {
#pragma unroll
        for (int j = 0; j < 4; ++j) {
          float z = fmaxf(acc[nb][j] + bcv[nb], 0.f);
          o0[j] = fmaf(z, w0[nb], o0[j]);
          o1[j] = fmaf(z, w1[nb], o1[j]);
        }
      }
#pragma unroll
      for (int j = 0; j < 4; ++j) {
        o0[j] += __shfl_xor(o0[j], 1, 64);
        o1[j] += __shfl_xor(o1[j], 1, 64);
        o0[j] += __shfl_xor(o0[j], 2, 64);
        o1[j] += __shfl_xor(o1[j], 2, 64);
        o0[j] += __shfl_xor(o0[j], 4, 64);
        o1[j] += __shfl_xor(o1[j], 4, 64);
        o0[j] += __shfl_xor(o0[j], 8, 64);
        o1[j] += __shfl_xor(o1[j], 8, 64);
      }
      if (m16 == 0) {
        long eb = base + grp * 16 + quad * 4;
        f32x4 oa = {o0[0] + ob0, o1[0] + ob1, o0[1] + ob0, o1[1] + ob1};
        f32x4 ob_ = {o0[2] + ob0, o1[2] + ob1, o0[3] + ob0, o1[3] + ob1};
        __builtin_nontemporal_store(oa, (f32x4*)(out + 2 * eb));
        __builtin_nontemporal_store(ob_, (f32x4*)(out + 2 * eb + 4));
      }
    }
  }
}

// ---------------- launch ----------------
extern "C" void kernel_launch(void* const* d_in, const int* in_sizes, int n_in,
                              void* d_out, int out_size, void* d_ws, size_t ws_size,
                              hipStream_t stream) {
  const float* x   = (const float*)d_in[0];
  const int*   ei  = (const int*)d_in[1];
  const float* W1  = (const float*)d_in[2];
  const float* b1  = (const float*)d_in[3];
  const float* W2  = (const float*)d_in[4];
  const float* b2  = (const float*)d_in[5];
  const float* Wc1 = (const float*)d_in[6];
  const float* bc1 = (const float*)d_in[7];
  const float* Wc2 = (const float*)d_in[8];
  const float* bc2 = (const float*)d_in[9];

  const int N = in_sizes[0] / 128;
  const int E = in_sizes[1] / 2;
  const int* src = ei;
  const int* dst = ei + E;

  const int nbkt = (N + BKT_NODES - 1) >> BKT_SHIFT;   // 98
  const int gsz = nbkt * PCHUNKS;                       // 50176
  const int chunk = (E + PCHUNKS - 1) / PCHUNKS;        // 3125

  // workspace layout
  float* dis     = (float*)d_ws;                   // N f32
  __half* y      = (__half*)(dis + N);             // (N+1)*64 f16 (sentinel row N)
  __half* h      = y + (long)(N + 1) * HID;        // N*64 f16
  __half* UV     = h + (long)N * HID;              // scratch region (aliased below)
  __half* packW1 = UV + (long)N * 128;             // 8192 f16
  __half* packW2 = packW1 + 8192;                  // 4096 f16
  __half* packUV = packW2 + 4096;                  // 8192 f16
  float* biasUV  = (float*)(packUV + 8192);        // 128 f32
  int* rowoff    = (int*)(biasUV + 128);           // N
  int* csr_src   = rowoff + N;                     // E
  int* G         = csr_src + E;                    // gsz
  int* Gs1       = G + gsz;                        // gsz
  int* Gbs       = Gs1 + gsz;                      // 128
  int* Gscan     = Gbs + 128;                      // gsz
  // partitioned edge arrays alias the (now otherwise unused) UV region
  int* psrc            = (int*)UV;                 // E ints (6.4MB < 25.6MB)
  unsigned short* pdst = (unsigned short*)(psrc + E);  // E u16

  const int B = 256;
  int nbScan = (gsz + 1023) / 1024;   // 49

  // ---- packing + bucketed CSR build (no global atomics) ----
  k_pack_all<<<11, B, 0, stream>>>(W1, W2, Wc1, bc1, packW1, packW2, packUV,
                                   biasUV, y + (long)N * HID);
  k_bkt_count<<<PCHUNKS, B, 0, stream>>>(dst, G, E, nbkt, chunk);
  k_scan1<<<nbScan, B, 0, stream>>>(G, Gs1, Gbs, gsz);
  k_scan2<<<1, 128, 0, stream>>>(Gbs, nbScan);
  k_scan3<<<(gsz + B - 1) / B, B, 0, stream>>>(Gs1, Gbs, Gscan, gsz);
  k_bkt_scatter<<<PCHUNKS, B, 0, stream>>>(src, dst, Gscan, psrc, pdst, E, nbkt,
                                           chunk);
  k_bkt_final<<<nbkt, 1024, 0, stream>>>(Gscan, psrc, pdst, rowoff, dis, csr_src,
                                         E, nbkt, N);

  int gAgg = (N + 3) / 4;
  int gLin = (N + 63) / 64;

  // ---- layer 1: y = (x@W1)*dis ; h = relu(dd*(y_self+sum y) + b1) ----
  k_lin_mfma<128, 64, true><<<gLin, B, 0, stream>>>(x, packW1, nullptr, dis, y, N);
  k_agg_csr<<<gAgg, B, 0, stream>>>(y, dis, rowoff, csr_src, b1, h, N, E, 1);

  // ---- layer 2 ----
  k_lin_mfma<64, 64, false><<<gLin, B, 0, stream>>>(h, packW2, nullptr, dis, y, N);
  k_agg_csr<<<gAgg, B, 0, stream>>>(y, dis, rowoff, csr_src, b2, h, N, E, 0);

  // ---- fused edge classifier: gathers h directly, 2-group pipelined MFMA ----
  int cblocks = 2048;
  int nwaves = cblocks * 4;
  k_edge_mfma<<<cblocks, B, 0, stream>>>(h, packUV, src, dst, bc1, Wc2, bc2,
                                         (float*)d_out, E, nwaves);
}